// Round 1
// baseline (1826.558 us; speedup 1.0000x reference)
//
#include <hip/hip_runtime.h>

static constexpr int NU = 100000;
static constexpr int NM = 20000;
static constexpr int NE = 3200000;
static constexpr int NL = 1000000;
static constexpr int FD = 128;
static constexpr int H  = 64;

// ---------------- CSR build ----------------
__global__ void k_hist(const int* __restrict__ esrc, const int* __restrict__ edst,
                       int* __restrict__ cnt_m, int* __restrict__ cnt_u) {
  int i = blockIdx.x * 256 + threadIdx.x;
  if (i < NE) {
    atomicAdd(&cnt_m[edst[i]], 1);
    atomicAdd(&cnt_u[esrc[i]], 1);
  }
}

__global__ void __launch_bounds__(1024) k_scan2(
    const int* __restrict__ cm, int* __restrict__ rpm, int* __restrict__ curm,
    const int* __restrict__ cu, int* __restrict__ rpu, int* __restrict__ curu) {
  const int* cnt; int* rp; int* cur; int n;
  if (blockIdx.x == 0) { cnt = cm; rp = rpm; cur = curm; n = NM; }
  else                 { cnt = cu; rp = rpu; cur = curu; n = NU; }
  __shared__ int wsum[17];
  __shared__ int carry_s;
  int tid = threadIdx.x;
  int lane = tid & 63, wid = tid >> 6;
  if (tid == 0) carry_s = 0;
  __syncthreads();
  for (int base = 0; base < n; base += 1024) {
    int idx = base + tid;
    int orig = (idx < n) ? cnt[idx] : 0;
    int v = orig;
    #pragma unroll
    for (int off = 1; off < 64; off <<= 1) {
      int t = __shfl_up(v, off, 64);
      if (lane >= off) v += t;
    }
    if (lane == 63) wsum[wid] = v;
    __syncthreads();
    if (wid == 0) {
      int w = (lane < 16) ? wsum[lane] : 0;
      #pragma unroll
      for (int off = 1; off < 16; off <<= 1) {
        int t = __shfl_up(w, off, 64);
        if (lane >= off) w += t;
      }
      if (lane < 16) wsum[lane] = w;
      if (lane == 15) wsum[16] = w;
    }
    __syncthreads();
    int carry = carry_s;
    int excl = carry + ((wid > 0) ? wsum[wid - 1] : 0) + (v - orig);
    if (idx < n) { rp[idx] = excl; cur[idx] = excl; }
    __syncthreads();
    if (tid == 0) carry_s += wsum[16];
    __syncthreads();
  }
  if (tid == 0) rp[n] = carry_s;
}

__global__ void k_scatter(const int* __restrict__ esrc, const int* __restrict__ edst,
                          int* __restrict__ cur_m, int* __restrict__ cur_u,
                          int* __restrict__ su_by_m, int* __restrict__ sm_by_u) {
  int i = blockIdx.x * 256 + threadIdx.x;
  if (i < NE) {
    int s = esrc[i], d = edst[i];
    int p = atomicAdd(&cur_m[d], 1);
    su_by_m[p] = s;
    int q = atomicAdd(&cur_u[s], 1);
    sm_by_u[q] = d;
  }
}

// ---------------- movie projection: out = x @ w + b ----------------
__global__ void __launch_bounds__(256) k_proj(const float* __restrict__ x,
                                              const float* __restrict__ w,
                                              const float* __restrict__ b,
                                              float* __restrict__ out) {
  __shared__ float sw[FD * H];   // 32 KB
  __shared__ float sx[4][FD];    // 2 KB
  int tid = threadIdx.x;
  int r0 = blockIdx.x * 4;
  #pragma unroll
  for (int it = 0; it < 8; ++it) {
    int idx = tid + it * 256;
    *(float4*)&sw[idx * 4] = ((const float4*)w)[idx];
  }
  if (tid < 128) {
    int row = tid >> 5, q = tid & 31;
    *(float4*)&sx[row][q * 4] = ((const float4*)x)[(size_t)(r0 + row) * 32 + q];
  }
  __syncthreads();
  int row = tid >> 6, col = tid & 63;
  float acc = b[col];
  #pragma unroll 8
  for (int k4 = 0; k4 < FD / 4; ++k4) {
    float4 a = *(const float4*)&sx[row][k4 * 4];
    acc += a.x * sw[(k4 * 4 + 0) * H + col];
    acc += a.y * sw[(k4 * 4 + 1) * H + col];
    acc += a.z * sw[(k4 * 4 + 2) * H + col];
    acc += a.w * sw[(k4 * 4 + 3) * H + col];
  }
  out[(size_t)(r0 + row) * H + col] = acc;
}

// ---------------- mean aggregation over CSR: one wave per dst node ----------------
__global__ void __launch_bounds__(256) k_agg(const float* __restrict__ feat,
                                             const int* __restrict__ rp,
                                             const int* __restrict__ idxs,
                                             float* __restrict__ out, int n) {
  int lane = threadIdx.x & 63;
  int d = blockIdx.x * 4 + (threadIdx.x >> 6);
  if (d >= n) return;
  int s = rp[d], e = rp[d + 1];
  float acc = 0.f;
  int i = s;
  for (; i + 4 <= e; i += 4) {
    int s0 = idxs[i + 0], s1 = idxs[i + 1], s2 = idxs[i + 2], s3 = idxs[i + 3];
    float f0 = feat[(size_t)s0 * H + lane];
    float f1 = feat[(size_t)s1 * H + lane];
    float f2 = feat[(size_t)s2 * H + lane];
    float f3 = feat[(size_t)s3 * H + lane];
    acc += f0; acc += f1; acc += f2; acc += f3;
  }
  for (; i < e; ++i) acc += feat[(size_t)idxs[i] * H + lane];
  out[(size_t)d * H + lane] = acc / fmaxf((float)(e - s), 1.f);
}

// ---------------- SAGE linear: out = agg@wl + bl + xdst@wr (+relu) ----------------
__global__ void __launch_bounds__(256) k_sage_lin(const float* __restrict__ agg,
                                                  const float* __restrict__ xdst,
                                                  const float* __restrict__ wl,
                                                  const float* __restrict__ wr,
                                                  const float* __restrict__ bl,
                                                  float* __restrict__ out,
                                                  int n, int relu) {
  __shared__ float swl[H * H];   // 16 KB
  __shared__ float swr[H * H];   // 16 KB
  __shared__ float sa[4][H];
  __shared__ float sd[4][H];
  int tid = threadIdx.x;
  int r0 = blockIdx.x * 4;
  #pragma unroll
  for (int it = 0; it < 4; ++it) {
    int idx = tid + it * 256;
    *(float4*)&swl[idx * 4] = ((const float4*)wl)[idx];
    *(float4*)&swr[idx * 4] = ((const float4*)wr)[idx];
  }
  if (tid < 64) {
    int row = tid >> 4, q = tid & 15;
    if (r0 + row < n)
      *(float4*)&sa[row][q * 4] = ((const float4*)agg)[(size_t)(r0 + row) * 16 + q];
  } else if (tid < 128) {
    int t = tid - 64;
    int row = t >> 4, q = t & 15;
    if (r0 + row < n)
      *(float4*)&sd[row][q * 4] = ((const float4*)xdst)[(size_t)(r0 + row) * 16 + q];
  }
  __syncthreads();
  int row = tid >> 6, col = tid & 63;
  if (r0 + row >= n) return;
  float acc = bl[col];
  #pragma unroll 8
  for (int k4 = 0; k4 < H / 4; ++k4) {
    float4 a = *(const float4*)&sa[row][k4 * 4];
    acc += a.x * swl[(k4 * 4 + 0) * H + col];
    acc += a.y * swl[(k4 * 4 + 1) * H + col];
    acc += a.z * swl[(k4 * 4 + 2) * H + col];
    acc += a.w * swl[(k4 * 4 + 3) * H + col];
  }
  #pragma unroll 8
  for (int k4 = 0; k4 < H / 4; ++k4) {
    float4 a = *(const float4*)&sd[row][k4 * 4];
    acc += a.x * swr[(k4 * 4 + 0) * H + col];
    acc += a.y * swr[(k4 * 4 + 1) * H + col];
    acc += a.z * swr[(k4 * 4 + 2) * H + col];
    acc += a.w * swr[(k4 * 4 + 3) * H + col];
  }
  if (relu) acc = fmaxf(acc, 0.f);
  out[(size_t)(r0 + row) * H + col] = acc;
}

// ---------------- fused edge decoder ----------------
__global__ void __launch_bounds__(256) k_decoder(const float* __restrict__ user2,
                                                 const float* __restrict__ movie2,
                                                 const int* __restrict__ lu,
                                                 const int* __restrict__ lm,
                                                 const float* __restrict__ w1,
                                                 const float* __restrict__ b1,
                                                 const float* __restrict__ w2,
                                                 const float* __restrict__ b2,
                                                 float* __restrict__ out) {
  __shared__ float sx[32][132];     // padded rows: ~16.9 KB
  __shared__ float sw1[2 * H * H];  // 32 KB
  __shared__ float sw2[H];
  __shared__ float sb1[H];
  __shared__ int slu[32], slm[32];
  int tid = threadIdx.x;
  int r0 = blockIdx.x * 32;
  if (tid < 32) slu[tid] = lu[r0 + tid];
  else if (tid < 64) slm[tid - 32] = lm[r0 + tid - 32];
  else if (tid < 128) sw2[tid - 64] = w2[tid - 64];
  else if (tid < 192) sb1[tid - 128] = b1[tid - 128];
  #pragma unroll
  for (int it = 0; it < 8; ++it) {
    int idx = tid + it * 256;
    *(float4*)&sw1[idx * 4] = ((const float4*)w1)[idx];
  }
  __syncthreads();
  #pragma unroll
  for (int it = 0; it < 4; ++it) {
    int idx = tid + it * 256;  // 1024 float4 = 32 rows * 32 groups
    int row = idx >> 5, q = idx & 31;
    float4 v;
    int c;
    if (q < 16) { v = ((const float4*)user2)[(size_t)slu[row] * 16 + q]; c = q * 4; }
    else        { v = ((const float4*)movie2)[(size_t)slm[row] * 16 + (q - 16)]; c = 64 + (q - 16) * 4; }
    *(float4*)&sx[row][c] = v;
  }
  __syncthreads();
  int cg = tid & 15, rp_ = tid >> 4;
  int c0 = cg * 4;
  float4 b1v = *(const float4*)&sb1[c0];
  float4 acc0 = b1v, acc1 = b1v;
  const float* x0 = sx[rp_ * 2];
  const float* x1 = sx[rp_ * 2 + 1];
  #pragma unroll 4
  for (int k = 0; k < 2 * H; ++k) {
    float a0 = x0[k], a1 = x1[k];
    float4 w = *(const float4*)&sw1[k * H + c0];
    acc0.x += a0 * w.x; acc0.y += a0 * w.y; acc0.z += a0 * w.z; acc0.w += a0 * w.w;
    acc1.x += a1 * w.x; acc1.y += a1 * w.y; acc1.z += a1 * w.z; acc1.w += a1 * w.w;
  }
  float4 w2v = *(const float4*)&sw2[c0];
  float p0 = fmaxf(acc0.x, 0.f) * w2v.x + fmaxf(acc0.y, 0.f) * w2v.y +
             fmaxf(acc0.z, 0.f) * w2v.z + fmaxf(acc0.w, 0.f) * w2v.w;
  float p1 = fmaxf(acc1.x, 0.f) * w2v.x + fmaxf(acc1.y, 0.f) * w2v.y +
             fmaxf(acc1.z, 0.f) * w2v.z + fmaxf(acc1.w, 0.f) * w2v.w;
  #pragma unroll
  for (int m = 8; m >= 1; m >>= 1) {
    p0 += __shfl_xor(p0, m, 64);
    p1 += __shfl_xor(p1, m, 64);
  }
  if (cg == 0) {
    float b2v = b2[0];
    out[(size_t)r0 + rp_ * 2 + 0] = p0 + b2v;
    out[(size_t)r0 + rp_ * 2 + 1] = p1 + b2v;
  }
}

extern "C" void kernel_launch(void* const* d_in, const int* in_sizes, int n_in,
                              void* d_out, int out_size, void* d_ws, size_t ws_size,
                              hipStream_t stream) {
  const float* movie_x  = (const float*)d_in[0];
  const int*   esrc     = (const int*)d_in[1];
  const int*   edst     = (const int*)d_in[2];
  const int*   lu       = (const int*)d_in[3];
  const int*   lm       = (const int*)d_in[4];
  const float* user_emb = (const float*)d_in[5];
  const float* proj_w   = (const float*)d_in[6];
  const float* proj_b   = (const float*)d_in[7];
  const float* dec_w1   = (const float*)d_in[8];
  const float* dec_b1   = (const float*)d_in[9];
  const float* dec_w2   = (const float*)d_in[10];
  const float* dec_b2   = (const float*)d_in[11];
  const float* w1_um_l  = (const float*)d_in[12];
  const float* b1_um_l  = (const float*)d_in[13];
  const float* w1_um_r  = (const float*)d_in[14];
  const float* w1_mu_l  = (const float*)d_in[15];
  const float* b1_mu_l  = (const float*)d_in[16];
  const float* w1_mu_r  = (const float*)d_in[17];
  const float* w2_um_l  = (const float*)d_in[18];
  const float* b2_um_l  = (const float*)d_in[19];
  const float* w2_um_r  = (const float*)d_in[20];
  const float* w2_mu_l  = (const float*)d_in[21];
  const float* b2_mu_l  = (const float*)d_in[22];
  const float* w2_mu_r  = (const float*)d_in[23];

  char* ws = (char*)d_ws;
  size_t off = 0;
  auto alloc = [&](size_t bytes) {
    void* p = ws + off;
    off = (off + bytes + 255) & ~(size_t)255;
    return p;
  };
  float* movie0  = (float*)alloc((size_t)NM * H * 4);
  float* movie1  = (float*)alloc((size_t)NM * H * 4);
  float* movie2  = (float*)alloc((size_t)NM * H * 4);
  float* user1   = (float*)alloc((size_t)NU * H * 4);
  float* user2   = (float*)alloc((size_t)NU * H * 4);
  float* agg_m   = (float*)alloc((size_t)NM * H * 4);
  float* agg_u   = (float*)alloc((size_t)NU * H * 4);
  int* rp_m      = (int*)alloc((size_t)(NM + 1) * 4);
  int* rp_u      = (int*)alloc((size_t)(NU + 1) * 4);
  int* cur_m     = (int*)alloc((size_t)NM * 4);
  int* cur_u     = (int*)alloc((size_t)NU * 4);
  int* cnt_m     = (int*)alloc((size_t)(NM + NU) * 4);  // cnt_m then cnt_u contiguous
  int* cnt_u     = cnt_m + NM;
  int* su_by_m   = (int*)alloc((size_t)NE * 4);
  int* sm_by_u   = (int*)alloc((size_t)NE * 4);
  (void)ws_size; (void)in_sizes; (void)n_in; (void)out_size;

  // CSR build
  hipMemsetAsync(cnt_m, 0, (size_t)(NM + NU) * 4, stream);
  int eblocks = (NE + 255) / 256;
  k_hist<<<eblocks, 256, 0, stream>>>(esrc, edst, cnt_m, cnt_u);
  k_scan2<<<2, 1024, 0, stream>>>(cnt_m, rp_m, cur_m, cnt_u, rp_u, cur_u);
  k_scatter<<<eblocks, 256, 0, stream>>>(esrc, edst, cur_m, cur_u, su_by_m, sm_by_u);

  // movie0 = movie_x @ proj_w + proj_b
  k_proj<<<NM / 4, 256, 0, stream>>>(movie_x, proj_w, proj_b, movie0);

  // conv1
  k_agg<<<(NM + 3) / 4, 256, 0, stream>>>(user_emb, rp_m, su_by_m, agg_m, NM);
  k_agg<<<(NU + 3) / 4, 256, 0, stream>>>(movie0, rp_u, sm_by_u, agg_u, NU);
  k_sage_lin<<<NM / 4, 256, 0, stream>>>(agg_m, movie0, w1_um_l, w1_um_r, b1_um_l, movie1, NM, 1);
  k_sage_lin<<<NU / 4, 256, 0, stream>>>(agg_u, user_emb, w1_mu_l, w1_mu_r, b1_mu_l, user1, NU, 1);

  // conv2
  k_agg<<<(NM + 3) / 4, 256, 0, stream>>>(user1, rp_m, su_by_m, agg_m, NM);
  k_agg<<<(NU + 3) / 4, 256, 0, stream>>>(movie1, rp_u, sm_by_u, agg_u, NU);
  k_sage_lin<<<NM / 4, 256, 0, stream>>>(agg_m, movie1, w2_um_l, w2_um_r, b2_um_l, movie2, NM, 0);
  k_sage_lin<<<NU / 4, 256, 0, stream>>>(agg_u, user1, w2_mu_l, w2_mu_r, b2_mu_l, user2, NU, 0);

  // decoder
  k_decoder<<<NL / 32, 256, 0, stream>>>(user2, movie2, lu, lm, dec_w1, dec_b1, dec_w2, dec_b2,
                                         (float*)d_out);
}